// Round 7
// baseline (704.360 us; speedup 1.0000x reference)
//
#include <hip/hip_runtime.h>
#include <stdint.h>

#define B_   16
#define L_   2048
#define D_   256
#define NROW (B_*L_)

#define EPAD 40    // Es row stride (shorts)
#define TPAD 66    // qkv transpose buffer row stride

typedef __attribute__((ext_vector_type(8))) short s8v;   // 8 x bf16 (as shorts)
typedef __attribute__((ext_vector_type(4))) float f4v;   // MFMA accumulator
typedef __attribute__((ext_vector_type(4))) float f4n;   // native float4 (NT stores)

__device__ __forceinline__ unsigned short f2b(float f) {   // RNE f32->bf16
    unsigned u = __builtin_bit_cast(unsigned, f);
    return (unsigned short)((u + 0x7fffu + ((u >> 16) & 1u)) >> 16);
}

// HW packed f32->bf16 (RNE): d.lo = bf16(a), d.hi = bf16(b)
__device__ __forceinline__ unsigned cvtpk(float a, float b) {
    unsigned r;
    asm("v_cvt_pk_bf16_f32 %0, %1, %2" : "=v"(r) : "v"(a), "v"(b));
    return r;
}

// async global->LDS, 16B per lane; LDS dest = wave-uniform base + lane*16
__device__ __forceinline__ void gl16(const void* g, void* l) {
    __builtin_amdgcn_global_load_lds(
        (const __attribute__((address_space(1))) unsigned int*)g,
        (__attribute__((address_space(3))) unsigned int*)l, 16, 0, 0);
}

template<int N> __device__ __forceinline__ void waitbar() {
    asm volatile("s_waitcnt vmcnt(%0)\n\ts_barrier" :: "i"(N) : "memory");
}
__device__ __forceinline__ void barOnly() {
    asm volatile("s_barrier" ::: "memory");
}

// -------- K0: pre-convert Wq/Wk/Wv fp32 -> bf16, pre-swizzled for gl16 ------
__global__ __launch_bounds__(256) void wconv_kernel(
    const float* __restrict__ Wq, const float* __restrict__ Wk,
    const float* __restrict__ Wv, unsigned short* __restrict__ Wb)
{
    const int t  = threadIdx.x;
    const int r0 = blockIdx.x * 64;
    const int wt = blockIdx.y;
    const float* W = wt == 0 ? Wq : (wt == 1 ? Wk : Wv);
    unsigned short* O = Wb + (size_t)wt * 256 * 256;
    #pragma unroll
    for (int p = 0; p < 16; ++p) {
        int idx  = p*256 + t;
        int row  = r0 + (idx >> 6);
        int half = idx & 1;
        int blk  = (idx & 63) >> 1;
        int c4   = blk*8 + half*4;
        float4 v = *(const float4*)(W + (size_t)row*D_ + c4);
        uint2 pw; pw.x = cvtpk(v.x, v.y); pw.y = cvtpk(v.z, v.w);
        *(uint2*)(O + row*256 + (blk ^ (row & 15))*8 + half*4) = pw;
    }
}

// weight half-tile (32x256 bf16, 16 KB) -> LDS via DMA, 4 chunks/thread
__device__ __forceinline__ void stage_W(const unsigned short* Wsrc, unsigned short* buf,
                                        int e0h, int w, int lane) {
    #pragma unroll
    for (int p = 0; p < 4; ++p) {
        int slot = p*256 + w*64 + lane;
        int row  = slot >> 5;
        int blk  = slot & 31;
        gl16(Wsrc + (size_t)(e0h + row)*256 + blk*8,
             buf + (size_t)(p*256 + w*64)*8);
    }
}

// ---------------- K1: QKV projection (pipelined weight DMA) ----------------
__global__ __launch_bounds__(256) void qkv_kernel(
    const float* __restrict__ x, const float* __restrict__ y,
    const unsigned short* __restrict__ Wb,
    unsigned short* __restrict__ Qb, unsigned short* __restrict__ Kb,
    unsigned short* __restrict__ Vt,
    float* __restrict__ qn, float* __restrict__ kn)
{
    __shared__ unsigned short Xs[64*256];      // 32 KB input tile (bf16)
    __shared__ unsigned short Wsb[2][32*256];  // 2 x 16 KB weight half-tiles
    __shared__ unsigned short Ts[64*TPAD];     // V transpose buffer

    const int t    = threadIdx.x;
    const int r0   = blockIdx.x * 64;
    const int type = blockIdx.y;        // 0=Q  1=K+V
    const float* X = type ? y : x;

    #pragma unroll
    for (int p = 0; p < 16; ++p) {
        int idx  = p*256 + t;
        int row  = idx >> 6;
        int half = idx & 1;
        int blk  = (idx & 63) >> 1;
        int c4   = blk*8 + half*4;
        float4 vx = *(const float4*)(X + (size_t)(r0+row)*D_ + c4);
        uint2 px; px.x = cvtpk(vx.x, vx.y); px.y = cvtpk(vx.z, vx.w);
        *(uint2*)(Xs + row*256 + (blk ^ (row & 15))*8 + half*4) = px;
    }

    const int w = t >> 6, lane = t & 63, q16 = lane & 15, quad = lane >> 4;
    const int m0 = w * 16;

    const unsigned short* W0 = Wb + (type ? 65536 : 0);
    const unsigned short* W1 = Wb + 131072;

    stage_W(W0, Wsb[0], 0,  w, lane);
    stage_W(W0, Wsb[1], 32, w, lane);

    asm volatile("s_waitcnt vmcnt(4) lgkmcnt(0)\n\ts_barrier" ::: "memory");

    s8v xa[8];
    #pragma unroll
    for (int c = 0; c < 8; ++c)
        xa[c] = *(const s8v*)(Xs + (m0 + q16)*256 + (((c*4+quad) ^ q16)*8));

    float p4[4] = {0.f, 0.f, 0.f, 0.f};
    const f4v z4 = {0.f, 0.f, 0.f, 0.f};
    f4v acc[4];

    auto compute_half = [&](int par) {
        #pragma unroll
        for (int c = 0; c < 8; ++c)
            #pragma unroll
            for (int nn = 0; nn < 2; ++nn) {
                s8v bb = *(const s8v*)(Wsb[par] + (nn*16 + q16)*256 + (((c*4+quad) ^ q16)*8));
                acc[par*2+nn] = __builtin_amdgcn_mfma_f32_16x16x32_bf16(xa[c], bb, acc[par*2+nn], 0, 0, 0);
            }
    };

    auto epi_qk = [&](int ct) {
        unsigned short* Out = type ? Kb : Qb;
        #pragma unroll
        for (int n = 0; n < 4; ++n)
            #pragma unroll
            for (int r = 0; r < 4; ++r) {
                float v = acc[n][r];
                p4[r] += v * v;
                Out[(size_t)(r0 + m0 + quad*4 + r)*D_ + ct*64 + n*16 + q16] = f2b(v);
            }
    };

    auto epi_v = [&](int ct) {
        #pragma unroll
        for (int n = 0; n < 4; ++n)
            #pragma unroll
            for (int r = 0; r < 4; ++r)
                Ts[(m0 + quad*4 + r)*TPAD + n*16 + q16] = f2b(acc[n][r]);
        asm volatile("s_waitcnt lgkmcnt(0)\n\ts_barrier" ::: "memory");
        int j = t >> 2, kseg = t & 3;
        unsigned pk[8];
        #pragma unroll
        for (int i = 0; i < 8; ++i) {
            unsigned lo = Ts[(kseg*16 + 2*i    )*TPAD + j];
            unsigned hi = Ts[(kseg*16 + 2*i + 1)*TPAD + j];
            pk[i] = lo | (hi << 16);
        }
        int bb_ = r0 >> 11, k0g = r0 & (L_ - 1);
        unsigned short* dst = Vt + (size_t)(bb_*D_ + ct*64 + j)*L_ + k0g + kseg*16;
        *(uint4*)dst       = make_uint4(pk[0], pk[1], pk[2], pk[3]);
        *((uint4*)dst + 1) = make_uint4(pk[4], pk[5], pk[6], pk[7]);
    };

    if (!type) {
        #pragma unroll
        for (int h = 0; h < 8; ++h) {
            if (h == 7)      waitbar<0>();
            else if (h > 0) { if (h & 1) waitbar<4>(); else waitbar<20>(); }
            const int par = h & 1;
            acc[par*2] = z4; acc[par*2+1] = z4;
            compute_half(par);
            if (par) epi_qk(h >> 1);
            barOnly();
            if (h + 2 < 8) stage_W(W0, Wsb[par], (h+2)*32, w, lane);
        }
    } else {
        #pragma unroll
        for (int h = 0; h < 16; ++h) {
            if (h == 15)     waitbar<0>();
            else if (h > 0) {
                if (h & 1)       waitbar<4>();
                else if (h <= 8) waitbar<20>();
                else             waitbar<6>();
            }
            const int par = h & 1;
            acc[par*2] = z4; acc[par*2+1] = z4;
            compute_half(par);
            if (par) { if (h < 8) epi_qk(h >> 1); else epi_v((h - 8) >> 1); }
            barOnly();
            if (h + 2 < 16) {
                const unsigned short* Ws_ = (h + 2 < 8) ? W0 : W1;
                stage_W(Ws_, Wsb[par], ((h + 2) & 7) * 32, w, lane);
            }
        }
    }

    {
        float* norm = type ? kn : qn;
        #pragma unroll
        for (int r = 0; r < 4; ++r) {
            float v = p4[r];
            v += __shfl_xor(v, 1, 16);
            v += __shfl_xor(v, 2, 16);
            v += __shfl_xor(v, 4, 16);
            v += __shfl_xor(v, 8, 16);
            if (q16 == 0) norm[r0 + m0 + quad*4 + r] = v;
        }
    }
}

// ---- staging helpers for 8-wave (512 thr) blocks ----
__device__ __forceinline__ void stage_K(const unsigned short* Kb, unsigned short* ks,
                                        int kb0, int k0, int w, int lane) {
    #pragma unroll
    for (int p = 0; p < 2; ++p) {
        int slot = p*512 + w*64 + lane;
        int row  = slot >> 5;
        int blk  = slot & 31;
        gl16(Kb + (size_t)(kb0 + k0 + row)*D_ + ((blk ^ (row & 15))*8),
             ks + (size_t)(p*512 + w*64)*8);
    }
}
// kg0 = global k offset within batch (kh*1024 + k0)
__device__ __forceinline__ void stage_V(const unsigned short* Vt, unsigned short* vs,
                                        int bD, int kg0, int w, int lane) {
    #pragma unroll
    for (int p = 0; p < 2; ++p) {
        int slot = p*512 + w*64 + lane;
        int d    = slot >> 2;
        int blk  = slot & 3;
        gl16(Vt + (size_t)(bD + d)*L_ + kg0 + ((blk ^ ((d >> 1) & 3))*8),
             vs + (size_t)(p*512 + w*64)*8);
    }
}

// -------- K2: attention core — 512 blocks, split-K(2), 2 blocks/CU --------
// Block = 128 q x 1024 k (32 tiles), 8 waves (Wq=16, R5's proven do_tile).
// LDS 79 KB (2-buffer ping-pong) + VGPR<=128 -> 2 blocks/CU = 16 waves/CU.
// Per tile: {vmcnt(1); s_barrier; stage(t+1); QK->softmax->NT E-export->PV}.
__global__ __launch_bounds__(512, 4) void attnpv_kernel(
    const unsigned short* __restrict__ Qb, const unsigned short* __restrict__ Kb,
    const unsigned short* __restrict__ Vt,
    const float* __restrict__ qn, const float* __restrict__ kn,
    const unsigned char* __restrict__ mask,
    unsigned short* __restrict__ Eb,
    float* __restrict__ rs2, float* __restrict__ Op)
{
    __shared__ unsigned short Ks[2][32*256];    // 2 x 16 KB
    __shared__ unsigned short Vs[2][256*32];    // 2 x 16 KB
    __shared__ unsigned short Es[8][16*EPAD];   // per-wave E tile (10 KB)
    __shared__ float         knS[1024];         // 4 KB (this k-half)
    __shared__ unsigned int  mkS4[256];         // 1 KB

    const int t  = threadIdx.x;
    // s bits: [8]=b-high, [7]=kh, [6:3]=q-chunk, [2:0]=XCD. 2 batches/XCD.
    const int s  = blockIdx.y * 32 + blockIdx.x;
    const int b  = ((s & 7) << 1) | (s >> 8);
    const int kh = (s >> 7) & 1;
    const int q0 = ((s >> 3) & 15) * 128;
    const int bk = b * L_;
    const int kb0 = bk + kh * 1024;     // flat row base of this k-half
    const int bD = b * D_;
    const int w = t >> 6, lane = t & 63, q16 = lane & 15, quad = lane >> 4;
    const int qrow = bk + q0 + w*16;

    *(float2*)&knS[t*2] = *(const float2*)&kn[kb0 + t*2];
    if (t < 256) mkS4[t] = *(const unsigned int*)(mask + kb0 + t*4);

    s8v qa[8];
    float qnr[4];
    #pragma unroll
    for (int c = 0; c < 8; ++c)
        qa[c] = *(const s8v*)(Qb + (size_t)(qrow + q16)*D_ + c*32 + quad*8);
    #pragma unroll
    for (int r = 0; r < 4; ++r)
        qnr[r] = qn[qrow + quad*4 + r];

    unsigned short* ebase = Eb + (size_t)(qrow + (lane >> 2))*L_ + kh*1024 + (lane & 3)*8;
    const unsigned short* esrc = &Es[w][(lane >> 2)*EPAD + (lane & 3)*8];

    float rs[4] = {0.f, 0.f, 0.f, 0.f};
    const f4v z4 = {0.f, 0.f, 0.f, 0.f};
    f4v O[16];
    #pragma unroll
    for (int n = 0; n < 16; ++n) O[n] = z4;

    auto do_tile = [&](int kt, const unsigned short* ksb, const unsigned short* vsb) {
        const int k0 = kt * 32;            // local k within this half
        float kcv[2]; int mkv[2];
        #pragma unroll
        for (int n = 0; n < 2; ++n) {
            kcv[n] = knS[k0 + n*16 + q16];
            mkv[n] = ((const unsigned char*)mkS4)[k0 + n*16 + q16];
        }
        #pragma unroll
        for (int n = 0; n < 2; ++n) {
            f4v s4 = z4;
            __builtin_amdgcn_s_setprio(1);
            #pragma unroll
            for (int c = 0; c < 8; ++c) {
                s8v bb = *(const s8v*)(ksb + (n*16 + q16)*256 + (((c*4+quad) ^ q16)*8));
                s4 = __builtin_amdgcn_mfma_f32_16x16x32_bf16(qa[c], bb, s4, 0, 0, 0);
            }
            __builtin_amdgcn_s_setprio(0);
            #pragma unroll
            for (int r = 0; r < 4; ++r) {
                float d2 = fmaf(-2.0f, s4[r], qnr[r] + kcv[n]);
                float dist = sqrtf(fmaxf(d2, 0.f));
                float E = mkv[n] ? 0.f : __expf(__expf(-dist));
                rs[r] += E;
                Es[w][(quad*4 + r)*EPAD + n*16 + q16] = f2b(E);
            }
        }
        // NT E-export issued BEFORE PV (overlaps 16 MFMAs; keeps K/V in L2)
        __builtin_nontemporal_store(*(const s8v*)esrc, (s8v*)(ebase + k0));
        s8v af = *(const s8v*)(&Es[w][q16*EPAD + quad*8]);
        __builtin_amdgcn_s_setprio(1);
        #pragma unroll
        for (int n = 0; n < 16; ++n) {
            s8v vb = *(const s8v*)(vsb + (n*16 + q16)*32 +
                                   ((quad ^ ((q16 >> 1) & 3))*8));
            O[n] = __builtin_amdgcn_mfma_f32_16x16x32_bf16(af, vb, O[n], 0, 0, 0);
        }
        __builtin_amdgcn_s_setprio(0);
    };

    // prologue: stage tiles 0 and 1 (ping-pong buffers)
    stage_K(Kb, Ks[0], kb0, 0,  w, lane);  stage_V(Vt, Vs[0], bD, kh*1024 + 0,  w, lane);
    stage_K(Kb, Ks[1], kb0, 32, w, lane);  stage_V(Vt, Vs[1], bD, kh*1024 + 32, w, lane);
    // drain qa/qn/kn/mask + stage(0); keep stage(1)'s 4 in flight
    asm volatile("s_waitcnt vmcnt(4) lgkmcnt(0)\n\ts_barrier" ::: "memory");
    do_tile(0, Ks[0], Vs[0]);

    for (int kt = 1; kt < 32; ++kt) {
        // outstanding: stage(kt)[4] + E(kt-1)[1] -> drain stage, keep E-store
        asm volatile("s_waitcnt vmcnt(1)\n\ts_barrier" ::: "memory");
        if (kt < 31) {
            const int nb = (kt + 1) & 1;   // buffer used by tile kt-1, now free
            stage_K(Kb, Ks[nb], kb0, (kt+1)*32, w, lane);
            stage_V(Vt, Vs[nb], bD, kh*1024 + (kt+1)*32, w, lane);
        }
        do_tile(kt, Ks[kt & 1], Vs[kt & 1]);
    }

    // epilogue: partial rowsum + raw partial O (combine+normalize in K3)
    #pragma unroll
    for (int r = 0; r < 4; ++r) {
        float v = rs[r];
        v += __shfl_xor(v, 1, 16);
        v += __shfl_xor(v, 2, 16);
        v += __shfl_xor(v, 4, 16);
        v += __shfl_xor(v, 8, 16);
        if (q16 == 0) rs2[(size_t)kh*NROW + qrow + quad*4 + r] = v;
    }
    #pragma unroll
    for (int n = 0; n < 16; ++n)
        #pragma unroll
        for (int r = 0; r < 4; ++r)
            __builtin_nontemporal_store(O[n][r],
                Op + (size_t)kh*NROW*D_ +
                    (size_t)(qrow + quad*4 + r)*D_ + n*16 + q16);
}

// -------- K3: combine + normalize --------
// One q-row per block: attn = E * inv (2048 cols) and
// att_out = (O0+O1) * inv (256 cols, threads 0..31), inv = 1/(rs0+rs1).
__global__ __launch_bounds__(256) void norm_kernel(
    const unsigned short* __restrict__ Eb,
    const float* __restrict__ rs2, const float* __restrict__ Op,
    float* __restrict__ att_out, float* __restrict__ attn_out)
{
    const int row = blockIdx.x;
    const int t   = threadIdx.x;
    const float inv = 1.0f / (rs2[row] + rs2[NROW + row]);
    const size_t base = (size_t)row * L_ + t*8;

    s8v e = __builtin_nontemporal_load((const s8v*)(Eb + base));
    f4n o0, o1;
    o0.x = __builtin_bit_cast(float, ((unsigned)(unsigned short)e[0]) << 16) * inv;
    o0.y = __builtin_bit_cast(float, ((unsigned)(unsigned short)e[1]) << 16) * inv;
    o0.z = __builtin_bit_cast(float, ((unsigned)(unsigned short)e[2]) << 16) * inv;
    o0.w = __builtin_bit_cast(float, ((unsigned)(unsigned short)e[3]) << 16) * inv;
    o1.x = __builtin_bit_cast(float, ((unsigned)(unsigned short)e[4]) << 16) * inv;
    o1.y = __builtin_bit_cast(float, ((unsigned)(unsigned short)e[5]) << 16) * inv;
    o1.z = __builtin_bit_cast(float, ((unsigned)(unsigned short)e[6]) << 16) * inv;
    o1.w = __builtin_bit_cast(float, ((unsigned)(unsigned short)e[7]) << 16) * inv;
    __builtin_nontemporal_store(o0, (f4n*)(attn_out + base));
    __builtin_nontemporal_store(o1, (f4n*)(attn_out + base + 4));

    if (t < 32) {
        const size_t ob = (size_t)row * D_ + t*8;
        f4n a0 = *(const f4n*)(Op + ob);
        f4n a1 = *(const f4n*)(Op + ob + 4);
        f4n b0 = *(const f4n*)(Op + (size_t)NROW*D_ + ob);
        f4n b1 = *(const f4n*)(Op + (size_t)NROW*D_ + ob + 4);
        f4n r0_ = (a0 + b0) * inv;
        f4n r1_ = (a1 + b1) * inv;
        __builtin_nontemporal_store(r0_, (f4n*)(att_out + ob));
        __builtin_nontemporal_store(r1_, (f4n*)(att_out + ob + 4));
    }
}

extern "C" void kernel_launch(void* const* d_in, const int* in_sizes, int n_in,
                              void* d_out, int out_size, void* d_ws, size_t ws_size,
                              hipStream_t stream) {
    (void)in_sizes; (void)n_in; (void)out_size; (void)ws_size;
    const float* x  = (const float*)d_in[0];
    const float* y  = (const float*)d_in[1];
    const unsigned char* mask = (const unsigned char*)d_in[2];
    const float* Wq = (const float*)d_in[3];
    const float* Wk = (const float*)d_in[4];
    const float* Wv = (const float*)d_in[5];

    // ws: Qb | Kb | Vt (bf16) | qn | kn | rs2[2N] (fp32) | Eb (bf16) | Op (f32 x2) | Wb
    char* ws = (char*)d_ws;
    unsigned short* Qb = (unsigned short*)ws;
    unsigned short* Kb = Qb + (size_t)NROW * D_;
    unsigned short* Vt = Kb + (size_t)NROW * D_;
    float* qn  = (float*)(ws + 3 * (size_t)NROW * D_ * 2);
    float* kn  = qn + NROW;
    float* rs2 = kn + NROW;                              // 2*NROW
    unsigned short* Eb = (unsigned short*)(rs2 + 2*(size_t)NROW);
    float* Op = (float*)(Eb + (size_t)NROW * L_);        // 2*NROW*D
    unsigned short* Wb = (unsigned short*)(Op + 2*(size_t)NROW*D_);

    float* att_out = (float*)d_out;                       // [B, LQ, D]
    float* attn    = att_out + (size_t)NROW * D_;         // [B, LQ, LK]

    wconv_kernel<<<dim3(4, 3), 256, 0, stream>>>(Wq, Wk, Wv, Wb);
    qkv_kernel<<<dim3(512, 2), 256, 0, stream>>>(x, y, Wb, Qb, Kb, Vt, qn, kn);
    attnpv_kernel<<<dim3(32, 16), 512, 0, stream>>>(Qb, Kb, Vt, qn, kn, mask,
                                                    Eb, rs2, Op);
    norm_kernel<<<dim3(NROW), 256, 0, stream>>>(Eb, rs2, Op, att_out, attn);
}

// Round 8
// 587.479 us; speedup vs baseline: 1.1990x; 1.1990x over previous
//
#include <hip/hip_runtime.h>
#include <stdint.h>

#define B_   16
#define L_   2048
#define D_   256
#define NROW (B_*L_)

#define EPAD 40    // Es row stride (shorts)
#define TPAD 66    // qkv transpose buffer row stride

typedef __attribute__((ext_vector_type(8))) short s8v;   // 8 x bf16 (as shorts)
typedef __attribute__((ext_vector_type(4))) float f4v;   // MFMA accumulator
typedef __attribute__((ext_vector_type(4))) float f4n;   // native float4 (NT stores)

__device__ __forceinline__ unsigned short f2b(float f) {   // RNE f32->bf16
    unsigned u = __builtin_bit_cast(unsigned, f);
    return (unsigned short)((u + 0x7fffu + ((u >> 16) & 1u)) >> 16);
}

// HW packed f32->bf16 (RNE): d.lo = bf16(a), d.hi = bf16(b)
__device__ __forceinline__ unsigned cvtpk(float a, float b) {
    unsigned r;
    asm("v_cvt_pk_bf16_f32 %0, %1, %2" : "=v"(r) : "v"(a), "v"(b));
    return r;
}

// async global->LDS, 16B per lane; LDS dest = wave-uniform base + lane*16
__device__ __forceinline__ void gl16(const void* g, void* l) {
    __builtin_amdgcn_global_load_lds(
        (const __attribute__((address_space(1))) unsigned int*)g,
        (__attribute__((address_space(3))) unsigned int*)l, 16, 0, 0);
}

template<int N> __device__ __forceinline__ void waitbar() {
    asm volatile("s_waitcnt vmcnt(%0)\n\ts_barrier" :: "i"(N) : "memory");
}
__device__ __forceinline__ void barOnly() {
    asm volatile("s_barrier" ::: "memory");
}

// -------- K0: pre-convert Wq/Wk/Wv fp32 -> bf16, pre-swizzled for gl16 ------
__global__ __launch_bounds__(256) void wconv_kernel(
    const float* __restrict__ Wq, const float* __restrict__ Wk,
    const float* __restrict__ Wv, unsigned short* __restrict__ Wb)
{
    const int t  = threadIdx.x;
    const int r0 = blockIdx.x * 64;
    const int wt = blockIdx.y;
    const float* W = wt == 0 ? Wq : (wt == 1 ? Wk : Wv);
    unsigned short* O = Wb + (size_t)wt * 256 * 256;
    #pragma unroll
    for (int p = 0; p < 16; ++p) {
        int idx  = p*256 + t;
        int row  = r0 + (idx >> 6);
        int half = idx & 1;
        int blk  = (idx & 63) >> 1;
        int c4   = blk*8 + half*4;
        float4 v = *(const float4*)(W + (size_t)row*D_ + c4);
        uint2 pw; pw.x = cvtpk(v.x, v.y); pw.y = cvtpk(v.z, v.w);
        *(uint2*)(O + row*256 + (blk ^ (row & 15))*8 + half*4) = pw;
    }
}

// weight half-tile (32x256 bf16, 16 KB) -> LDS via DMA, 4 chunks/thread
__device__ __forceinline__ void stage_W(const unsigned short* Wsrc, unsigned short* buf,
                                        int e0h, int w, int lane) {
    #pragma unroll
    for (int p = 0; p < 4; ++p) {
        int slot = p*256 + w*64 + lane;
        int row  = slot >> 5;
        int blk  = slot & 31;
        gl16(Wsrc + (size_t)(e0h + row)*256 + blk*8,
             buf + (size_t)(p*256 + w*64)*8);
    }
}

// ---------------- K1: QKV projection (pipelined weight DMA) ----------------
__global__ __launch_bounds__(256) void qkv_kernel(
    const float* __restrict__ x, const float* __restrict__ y,
    const unsigned short* __restrict__ Wb,
    unsigned short* __restrict__ Qb, unsigned short* __restrict__ Kb,
    unsigned short* __restrict__ Vt,
    float* __restrict__ qn, float* __restrict__ kn)
{
    __shared__ unsigned short Xs[64*256];      // 32 KB input tile (bf16)
    __shared__ unsigned short Wsb[2][32*256];  // 2 x 16 KB weight half-tiles
    __shared__ unsigned short Ts[64*TPAD];     // V transpose buffer

    const int t    = threadIdx.x;
    const int r0   = blockIdx.x * 64;
    const int type = blockIdx.y;        // 0=Q  1=K+V
    const float* X = type ? y : x;

    #pragma unroll
    for (int p = 0; p < 16; ++p) {
        int idx  = p*256 + t;
        int row  = idx >> 6;
        int half = idx & 1;
        int blk  = (idx & 63) >> 1;
        int c4   = blk*8 + half*4;
        float4 vx = *(const float4*)(X + (size_t)(r0+row)*D_ + c4);
        uint2 px; px.x = cvtpk(vx.x, vx.y); px.y = cvtpk(vx.z, vx.w);
        *(uint2*)(Xs + row*256 + (blk ^ (row & 15))*8 + half*4) = px;
    }

    const int w = t >> 6, lane = t & 63, q16 = lane & 15, quad = lane >> 4;
    const int m0 = w * 16;

    const unsigned short* W0 = Wb + (type ? 65536 : 0);
    const unsigned short* W1 = Wb + 131072;

    stage_W(W0, Wsb[0], 0,  w, lane);
    stage_W(W0, Wsb[1], 32, w, lane);

    asm volatile("s_waitcnt vmcnt(4) lgkmcnt(0)\n\ts_barrier" ::: "memory");

    s8v xa[8];
    #pragma unroll
    for (int c = 0; c < 8; ++c)
        xa[c] = *(const s8v*)(Xs + (m0 + q16)*256 + (((c*4+quad) ^ q16)*8));

    float p4[4] = {0.f, 0.f, 0.f, 0.f};
    const f4v z4 = {0.f, 0.f, 0.f, 0.f};
    f4v acc[4];

    auto compute_half = [&](int par) {
        #pragma unroll
        for (int c = 0; c < 8; ++c)
            #pragma unroll
            for (int nn = 0; nn < 2; ++nn) {
                s8v bb = *(const s8v*)(Wsb[par] + (nn*16 + q16)*256 + (((c*4+quad) ^ q16)*8));
                acc[par*2+nn] = __builtin_amdgcn_mfma_f32_16x16x32_bf16(xa[c], bb, acc[par*2+nn], 0, 0, 0);
            }
    };

    auto epi_qk = [&](int ct) {
        unsigned short* Out = type ? Kb : Qb;
        #pragma unroll
        for (int n = 0; n < 4; ++n)
            #pragma unroll
            for (int r = 0; r < 4; ++r) {
                float v = acc[n][r];
                p4[r] += v * v;
                Out[(size_t)(r0 + m0 + quad*4 + r)*D_ + ct*64 + n*16 + q16] = f2b(v);
            }
    };

    auto epi_v = [&](int ct) {
        #pragma unroll
        for (int n = 0; n < 4; ++n)
            #pragma unroll
            for (int r = 0; r < 4; ++r)
                Ts[(m0 + quad*4 + r)*TPAD + n*16 + q16] = f2b(acc[n][r]);
        asm volatile("s_waitcnt lgkmcnt(0)\n\ts_barrier" ::: "memory");
        int j = t >> 2, kseg = t & 3;
        unsigned pk[8];
        #pragma unroll
        for (int i = 0; i < 8; ++i) {
            unsigned lo = Ts[(kseg*16 + 2*i    )*TPAD + j];
            unsigned hi = Ts[(kseg*16 + 2*i + 1)*TPAD + j];
            pk[i] = lo | (hi << 16);
        }
        int bb_ = r0 >> 11, k0g = r0 & (L_ - 1);
        unsigned short* dst = Vt + (size_t)(bb_*D_ + ct*64 + j)*L_ + k0g + kseg*16;
        *(uint4*)dst       = make_uint4(pk[0], pk[1], pk[2], pk[3]);
        *((uint4*)dst + 1) = make_uint4(pk[4], pk[5], pk[6], pk[7]);
    };

    if (!type) {
        #pragma unroll
        for (int h = 0; h < 8; ++h) {
            if (h == 7)      waitbar<0>();
            else if (h > 0) { if (h & 1) waitbar<4>(); else waitbar<20>(); }
            const int par = h & 1;
            acc[par*2] = z4; acc[par*2+1] = z4;
            compute_half(par);
            if (par) epi_qk(h >> 1);
            barOnly();
            if (h + 2 < 8) stage_W(W0, Wsb[par], (h+2)*32, w, lane);
        }
    } else {
        #pragma unroll
        for (int h = 0; h < 16; ++h) {
            if (h == 15)     waitbar<0>();
            else if (h > 0) {
                if (h & 1)       waitbar<4>();
                else if (h <= 8) waitbar<20>();
                else             waitbar<6>();
            }
            const int par = h & 1;
            acc[par*2] = z4; acc[par*2+1] = z4;
            compute_half(par);
            if (par) { if (h < 8) epi_qk(h >> 1); else epi_v((h - 8) >> 1); }
            barOnly();
            if (h + 2 < 16) {
                const unsigned short* Ws_ = (h + 2 < 8) ? W0 : W1;
                stage_W(Ws_, Wsb[par], ((h + 2) & 7) * 32, w, lane);
            }
        }
    }

    {
        float* norm = type ? kn : qn;
        #pragma unroll
        for (int r = 0; r < 4; ++r) {
            float v = p4[r];
            v += __shfl_xor(v, 1, 16);
            v += __shfl_xor(v, 2, 16);
            v += __shfl_xor(v, 4, 16);
            v += __shfl_xor(v, 8, 16);
            if (q16 == 0) norm[r0 + m0 + quad*4 + r] = v;
        }
    }
}

// ---- staging helpers for 8-wave (512 thr) blocks ----
__device__ __forceinline__ void stage_K(const unsigned short* Kb, unsigned short* ks,
                                        int kb0, int k0, int w, int lane) {
    #pragma unroll
    for (int p = 0; p < 2; ++p) {
        int slot = p*512 + w*64 + lane;
        int row  = slot >> 5;
        int blk  = slot & 31;
        gl16(Kb + (size_t)(kb0 + k0 + row)*D_ + ((blk ^ (row & 15))*8),
             ks + (size_t)(p*512 + w*64)*8);
    }
}
// kg0 = global k offset within batch (kh*1024 + k0)
__device__ __forceinline__ void stage_V(const unsigned short* Vt, unsigned short* vs,
                                        int bD, int kg0, int w, int lane) {
    #pragma unroll
    for (int p = 0; p < 2; ++p) {
        int slot = p*512 + w*64 + lane;
        int d    = slot >> 2;
        int blk  = slot & 3;
        gl16(Vt + (size_t)(bD + d)*L_ + kg0 + ((blk ^ ((d >> 1) & 3))*8),
             vs + (size_t)(p*512 + w*64)*8);
    }
}

// -------- K2: attention core — 512 blocks, split-K(2), 2 blocks/CU --------
// Block = 128 q x 1024 k (32 tiles), 8 waves (Wq=16).  LDS 79 KB.
// __launch_bounds__(512, 2): hipcc treats arg2 as min blocks/CU (R7 post-
// mortem: (512,4) capped VGPR at 64 -> O[16] spilled, 750 MB scratch traffic).
// (512,2) -> 128 VGPR cap; kernel needs ~105 -> no spill, 2 blocks/CU.
__global__ __launch_bounds__(512, 2) void attnpv_kernel(
    const unsigned short* __restrict__ Qb, const unsigned short* __restrict__ Kb,
    const unsigned short* __restrict__ Vt,
    const float* __restrict__ qn, const float* __restrict__ kn,
    const unsigned char* __restrict__ mask,
    unsigned short* __restrict__ Eb,
    float* __restrict__ rs2, float* __restrict__ Op)
{
    __shared__ unsigned short Ks[2][32*256];    // 2 x 16 KB
    __shared__ unsigned short Vs[2][256*32];    // 2 x 16 KB
    __shared__ unsigned short Es[8][16*EPAD];   // per-wave E tile (10 KB)
    __shared__ float         knS[1024];         // 4 KB (this k-half)
    __shared__ unsigned int  mkS4[256];         // 1 KB

    const int t  = threadIdx.x;
    // s bits: [8]=b-high, [7]=kh, [6:3]=q-chunk, [2:0]=XCD. 2 batches/XCD.
    const int s  = blockIdx.y * 32 + blockIdx.x;
    const int b  = ((s & 7) << 1) | (s >> 8);
    const int kh = (s >> 7) & 1;
    const int q0 = ((s >> 3) & 15) * 128;
    const int bk = b * L_;
    const int kb0 = bk + kh * 1024;     // flat row base of this k-half
    const int bD = b * D_;
    const int w = t >> 6, lane = t & 63, q16 = lane & 15, quad = lane >> 4;
    const int qrow = bk + q0 + w*16;

    *(float2*)&knS[t*2] = *(const float2*)&kn[kb0 + t*2];
    if (t < 256) mkS4[t] = *(const unsigned int*)(mask + kb0 + t*4);

    s8v qa[8];
    float qnr[4];
    #pragma unroll
    for (int c = 0; c < 8; ++c)
        qa[c] = *(const s8v*)(Qb + (size_t)(qrow + q16)*D_ + c*32 + quad*8);
    #pragma unroll
    for (int r = 0; r < 4; ++r)
        qnr[r] = qn[qrow + quad*4 + r];

    unsigned short* ebase = Eb + (size_t)(qrow + (lane >> 2))*L_ + kh*1024 + (lane & 3)*8;
    const unsigned short* esrc = &Es[w][(lane >> 2)*EPAD + (lane & 3)*8];

    float rs[4] = {0.f, 0.f, 0.f, 0.f};
    const f4v z4 = {0.f, 0.f, 0.f, 0.f};
    f4v O[16];
    #pragma unroll
    for (int n = 0; n < 16; ++n) O[n] = z4;

    auto do_tile = [&](int kt, const unsigned short* ksb, const unsigned short* vsb) {
        const int k0 = kt * 32;            // local k within this half
        float kcv[2]; int mkv[2];
        #pragma unroll
        for (int n = 0; n < 2; ++n) {
            kcv[n] = knS[k0 + n*16 + q16];
            mkv[n] = ((const unsigned char*)mkS4)[k0 + n*16 + q16];
        }
        #pragma unroll
        for (int n = 0; n < 2; ++n) {
            f4v s4 = z4;
            __builtin_amdgcn_s_setprio(1);
            #pragma unroll
            for (int c = 0; c < 8; ++c) {
                s8v bb = *(const s8v*)(ksb + (n*16 + q16)*256 + (((c*4+quad) ^ q16)*8));
                s4 = __builtin_amdgcn_mfma_f32_16x16x32_bf16(qa[c], bb, s4, 0, 0, 0);
            }
            __builtin_amdgcn_s_setprio(0);
            #pragma unroll
            for (int r = 0; r < 4; ++r) {
                float d2 = fmaf(-2.0f, s4[r], qnr[r] + kcv[n]);
                float dist = sqrtf(fmaxf(d2, 0.f));
                float E = mkv[n] ? 0.f : __expf(__expf(-dist));
                rs[r] += E;
                Es[w][(quad*4 + r)*EPAD + n*16 + q16] = f2b(E);
            }
        }
        // NT E-export issued BEFORE PV (overlaps 16 MFMAs; keeps K/V in L2)
        __builtin_nontemporal_store(*(const s8v*)esrc, (s8v*)(ebase + k0));
        s8v af = *(const s8v*)(&Es[w][q16*EPAD + quad*8]);
        __builtin_amdgcn_s_setprio(1);
        #pragma unroll
        for (int n = 0; n < 16; ++n) {
            s8v vb = *(const s8v*)(vsb + (n*16 + q16)*32 +
                                   ((quad ^ ((q16 >> 1) & 3))*8));
            O[n] = __builtin_amdgcn_mfma_f32_16x16x32_bf16(af, vb, O[n], 0, 0, 0);
        }
        __builtin_amdgcn_s_setprio(0);
    };

    // prologue: stage tiles 0 and 1 (ping-pong buffers)
    stage_K(Kb, Ks[0], kb0, 0,  w, lane);  stage_V(Vt, Vs[0], bD, kh*1024 + 0,  w, lane);
    stage_K(Kb, Ks[1], kb0, 32, w, lane);  stage_V(Vt, Vs[1], bD, kh*1024 + 32, w, lane);
    // drain qa/qn/kn/mask + stage(0); keep stage(1)'s 4 in flight
    asm volatile("s_waitcnt vmcnt(4) lgkmcnt(0)\n\ts_barrier" ::: "memory");
    do_tile(0, Ks[0], Vs[0]);

    for (int kt = 1; kt < 32; ++kt) {
        // outstanding: stage(kt)[4] + E(kt-1)[1] -> drain stage, keep E-store
        asm volatile("s_waitcnt vmcnt(1)\n\ts_barrier" ::: "memory");
        if (kt < 31) {
            const int nb = (kt + 1) & 1;   // buffer used by tile kt-1, now free
            stage_K(Kb, Ks[nb], kb0, (kt+1)*32, w, lane);
            stage_V(Vt, Vs[nb], bD, kh*1024 + (kt+1)*32, w, lane);
        }
        do_tile(kt, Ks[kt & 1], Vs[kt & 1]);
    }

    // epilogue: partial rowsum + raw partial O (combine+normalize in K3)
    #pragma unroll
    for (int r = 0; r < 4; ++r) {
        float v = rs[r];
        v += __shfl_xor(v, 1, 16);
        v += __shfl_xor(v, 2, 16);
        v += __shfl_xor(v, 4, 16);
        v += __shfl_xor(v, 8, 16);
        if (q16 == 0) rs2[(size_t)kh*NROW + qrow + quad*4 + r] = v;
    }
    #pragma unroll
    for (int n = 0; n < 16; ++n)
        #pragma unroll
        for (int r = 0; r < 4; ++r)
            __builtin_nontemporal_store(O[n][r],
                Op + (size_t)kh*NROW*D_ +
                    (size_t)(qrow + quad*4 + r)*D_ + n*16 + q16);
}

// -------- K3: combine + normalize --------
// One q-row per block: attn = E * inv (2048 cols) and
// att_out = (O0+O1) * inv (256 cols, threads 0..31), inv = 1/(rs0+rs1).
__global__ __launch_bounds__(256) void norm_kernel(
    const unsigned short* __restrict__ Eb,
    const float* __restrict__ rs2, const float* __restrict__ Op,
    float* __restrict__ att_out, float* __restrict__ attn_out)
{
    const int row = blockIdx.x;
    const int t   = threadIdx.x;
    const float inv = 1.0f / (rs2[row] + rs2[NROW + row]);
    const size_t base = (size_t)row * L_ + t*8;

    s8v e = __builtin_nontemporal_load((const s8v*)(Eb + base));
    f4n o0, o1;
    o0.x = __builtin_bit_cast(float, ((unsigned)(unsigned short)e[0]) << 16) * inv;
    o0.y = __builtin_bit_cast(float, ((unsigned)(unsigned short)e[1]) << 16) * inv;
    o0.z = __builtin_bit_cast(float, ((unsigned)(unsigned short)e[2]) << 16) * inv;
    o0.w = __builtin_bit_cast(float, ((unsigned)(unsigned short)e[3]) << 16) * inv;
    o1.x = __builtin_bit_cast(float, ((unsigned)(unsigned short)e[4]) << 16) * inv;
    o1.y = __builtin_bit_cast(float, ((unsigned)(unsigned short)e[5]) << 16) * inv;
    o1.z = __builtin_bit_cast(float, ((unsigned)(unsigned short)e[6]) << 16) * inv;
    o1.w = __builtin_bit_cast(float, ((unsigned)(unsigned short)e[7]) << 16) * inv;
    __builtin_nontemporal_store(o0, (f4n*)(attn_out + base));
    __builtin_nontemporal_store(o1, (f4n*)(attn_out + base + 4));

    if (t < 32) {
        const size_t ob = (size_t)row * D_ + t*8;
        f4n a0 = *(const f4n*)(Op + ob);
        f4n a1 = *(const f4n*)(Op + ob + 4);
        f4n b0 = *(const f4n*)(Op + (size_t)NROW*D_ + ob);
        f4n b1 = *(const f4n*)(Op + (size_t)NROW*D_ + ob + 4);
        f4n r0_ = (a0 + b0) * inv;
        f4n r1_ = (a1 + b1) * inv;
        __builtin_nontemporal_store(r0_, (f4n*)(att_out + ob));
        __builtin_nontemporal_store(r1_, (f4n*)(att_out + ob + 4));
    }
}

extern "C" void kernel_launch(void* const* d_in, const int* in_sizes, int n_in,
                              void* d_out, int out_size, void* d_ws, size_t ws_size,
                              hipStream_t stream) {
    (void)in_sizes; (void)n_in; (void)out_size; (void)ws_size;
    const float* x  = (const float*)d_in[0];
    const float* y  = (const float*)d_in[1];
    const unsigned char* mask = (const unsigned char*)d_in[2];
    const float* Wq = (const float*)d_in[3];
    const float* Wk = (const float*)d_in[4];
    const float* Wv = (const float*)d_in[5];

    // ws: Qb | Kb | Vt (bf16) | qn | kn | rs2[2N] (fp32) | Eb (bf16) | Op (f32 x2) | Wb
    char* ws = (char*)d_ws;
    unsigned short* Qb = (unsigned short*)ws;
    unsigned short* Kb = Qb + (size_t)NROW * D_;
    unsigned short* Vt = Kb + (size_t)NROW * D_;
    float* qn  = (float*)(ws + 3 * (size_t)NROW * D_ * 2);
    float* kn  = qn + NROW;
    float* rs2 = kn + NROW;                              // 2*NROW
    unsigned short* Eb = (unsigned short*)(rs2 + 2*(size_t)NROW);
    float* Op = (float*)(Eb + (size_t)NROW * L_);        // 2*NROW*D
    unsigned short* Wb = (unsigned short*)(Op + 2*(size_t)NROW*D_);

    float* att_out = (float*)d_out;                       // [B, LQ, D]
    float* attn    = att_out + (size_t)NROW * D_;         // [B, LQ, LK]

    wconv_kernel<<<dim3(4, 3), 256, 0, stream>>>(Wq, Wk, Wv, Wb);
    qkv_kernel<<<dim3(512, 2), 256, 0, stream>>>(x, y, Wb, Qb, Kb, Vt, qn, kn);
    attnpv_kernel<<<dim3(32, 16), 512, 0, stream>>>(Qb, Kb, Vt, qn, kn, mask,
                                                    Eb, rs2, Op);
    norm_kernel<<<dim3(NROW), 256, 0, stream>>>(Eb, rs2, Op, att_out, attn);
}

// Round 11
// 565.129 us; speedup vs baseline: 1.2464x; 1.0395x over previous
//
#include <hip/hip_runtime.h>
#include <stdint.h>

#define B_   16
#define L_   2048
#define D_   256
#define NROW (B_*L_)

#define EPAD 40    // Es row stride (shorts)
#define TPAD 66    // qkv transpose buffer row stride

typedef __attribute__((ext_vector_type(8))) short s8v;   // 8 x bf16 (as shorts)
typedef __attribute__((ext_vector_type(4))) float f4v;   // MFMA accumulator
typedef __attribute__((ext_vector_type(4))) float f4n;   // native float4 (NT stores)

__device__ __forceinline__ unsigned short f2b(float f) {   // RNE f32->bf16
    unsigned u = __builtin_bit_cast(unsigned, f);
    return (unsigned short)((u + 0x7fffu + ((u >> 16) & 1u)) >> 16);
}

// HW packed f32->bf16 (RNE): d.lo = bf16(a), d.hi = bf16(b)
__device__ __forceinline__ unsigned cvtpk(float a, float b) {
    unsigned r;
    asm("v_cvt_pk_bf16_f32 %0, %1, %2" : "=v"(r) : "v"(a), "v"(b));
    return r;
}

// async global->LDS, 16B per lane; LDS dest = wave-uniform base + lane*16
__device__ __forceinline__ void gl16(const void* g, void* l) {
    __builtin_amdgcn_global_load_lds(
        (const __attribute__((address_space(1))) unsigned int*)g,
        (__attribute__((address_space(3))) unsigned int*)l, 16, 0, 0);
}

template<int N> __device__ __forceinline__ void waitbar() {
    asm volatile("s_waitcnt vmcnt(%0)\n\ts_barrier" :: "i"(N) : "memory");
}
__device__ __forceinline__ void barOnly() {
    asm volatile("s_barrier" ::: "memory");
}

// -------- K0: pre-convert Wq/Wk/Wv fp32 -> bf16, pre-swizzled for gl16 ------
// Wb layout: [3][256 rows e][32 chunks of 16B], chunk at pos (blk ^ (e&15)).
__global__ __launch_bounds__(256) void wconv_kernel(
    const float* __restrict__ Wq, const float* __restrict__ Wk,
    const float* __restrict__ Wv, unsigned short* __restrict__ Wb)
{
    const int t  = threadIdx.x;
    const int r0 = blockIdx.x * 64;
    const int wt = blockIdx.y;
    const float* W = wt == 0 ? Wq : (wt == 1 ? Wk : Wv);
    unsigned short* O = Wb + (size_t)wt * 256 * 256;
    #pragma unroll
    for (int p = 0; p < 16; ++p) {
        int idx  = p*256 + t;
        int row  = r0 + (idx >> 6);
        int half = idx & 1;
        int blk  = (idx & 63) >> 1;
        int c4   = blk*8 + half*4;
        float4 v = *(const float4*)(W + (size_t)row*D_ + c4);
        uint2 pw; pw.x = cvtpk(v.x, v.y); pw.y = cvtpk(v.z, v.w);
        *(uint2*)(O + row*256 + (blk ^ (row & 15))*8 + half*4) = pw;
    }
}

// weight half-tile (32 rows x 256 cols bf16, 16 KB) -> LDS via DMA (linear copy,
// swizzle already applied in Wb). 4 chunks per thread.
__device__ __forceinline__ void stage_W(const unsigned short* Wsrc, unsigned short* buf,
                                        int e0h, int w, int lane) {
    #pragma unroll
    for (int p = 0; p < 4; ++p) {
        int slot = p*256 + w*64 + lane;
        int row  = slot >> 5;      // 0..31
        int blk  = slot & 31;
        gl16(Wsrc + (size_t)(e0h + row)*256 + blk*8,
             buf + (size_t)(p*256 + w*64)*8);
    }
}

// ---------------- K1: QKV projection (pipelined weight DMA) ----------------
// grid (512 row-blocks, 2 types), block 256 (4 waves), 2 blocks/CU.
// type0: Q (8 half-phases).  type1: K then V (16 half-phases), y staged once.
// Per phase: {counted vmcnt; barrier; 16 MFMA (+epilogue on odd); barrier;
//             DMA-prefetch half-tile h+2}.  Weight stores never VALU-converted.
__global__ __launch_bounds__(256) void qkv_kernel(
    const float* __restrict__ x, const float* __restrict__ y,
    const unsigned short* __restrict__ Wb,
    unsigned short* __restrict__ Qb, unsigned short* __restrict__ Kb,
    unsigned short* __restrict__ Vt,
    float* __restrict__ qn, float* __restrict__ kn)
{
    __shared__ unsigned short Xs[64*256];      // 32 KB input tile (bf16)
    __shared__ unsigned short Wsb[2][32*256];  // 2 x 16 KB weight half-tiles
    __shared__ unsigned short Ts[64*TPAD];     // V transpose buffer (8.4 KB)

    const int t    = threadIdx.x;
    const int r0   = blockIdx.x * 64;   // global row (flat b*L + pos)
    const int type = blockIdx.y;        // 0=Q  1=K+V
    const float* X = type ? y : x;

    // Stage X tile [64][256] fp32 -> bf16 LDS, 16B-chunk swizzled by row&15.
    #pragma unroll
    for (int p = 0; p < 16; ++p) {
        int idx  = p*256 + t;
        int row  = idx >> 6;
        int half = idx & 1;
        int blk  = (idx & 63) >> 1;
        int c4   = blk*8 + half*4;
        float4 vx = *(const float4*)(X + (size_t)(r0+row)*D_ + c4);
        uint2 px; px.x = cvtpk(vx.x, vx.y); px.y = cvtpk(vx.z, vx.w);
        *(uint2*)(Xs + row*256 + (blk ^ (row & 15))*8 + half*4) = px;
    }

    const int w = t >> 6, lane = t & 63, q16 = lane & 15, quad = lane >> 4;
    const int m0 = w * 16;

    const unsigned short* W0 = Wb + (type ? 65536 : 0);   // Wq or Wk
    const unsigned short* W1 = Wb + 131072;               // Wv

    stage_W(W0, Wsb[0], 0,  w, lane);   // H0
    stage_W(W0, Wsb[1], 32, w, lane);   // H1

    // phase 0 entry: drain H0 (keep H1), Xs ds-writes visible
    asm volatile("s_waitcnt vmcnt(4) lgkmcnt(0)\n\ts_barrier" ::: "memory");

    // hoist A-fragments (reused in every phase)
    s8v xa[8];
    #pragma unroll
    for (int c = 0; c < 8; ++c)
        xa[c] = *(const s8v*)(Xs + (m0 + q16)*256 + (((c*4+quad) ^ q16)*8));

    float p4[4] = {0.f, 0.f, 0.f, 0.f};
    const f4v z4 = {0.f, 0.f, 0.f, 0.f};
    f4v acc[4];

    auto compute_half = [&](int par) {   // fills acc[par*2 + nn] from Wsb[par]
        #pragma unroll
        for (int c = 0; c < 8; ++c)
            #pragma unroll
            for (int nn = 0; nn < 2; ++nn) {
                s8v bb = *(const s8v*)(Wsb[par] + (nn*16 + q16)*256 + (((c*4+quad) ^ q16)*8));
                acc[par*2+nn] = __builtin_amdgcn_mfma_f32_16x16x32_bf16(xa[c], bb, acc[par*2+nn], 0, 0, 0);
            }
    };

    auto epi_qk = [&](int ct) {          // 16 b16 stores
        unsigned short* Out = type ? Kb : Qb;
        #pragma unroll
        for (int n = 0; n < 4; ++n)
            #pragma unroll
            for (int r = 0; r < 4; ++r) {
                float v = acc[n][r];
                p4[r] += v * v;
                Out[(size_t)(r0 + m0 + quad*4 + r)*D_ + ct*64 + n*16 + q16] = f2b(v);
            }
    };

    auto epi_v = [&](int ct) {           // transpose via Ts, 2 dwordx4 stores
        #pragma unroll
        for (int n = 0; n < 4; ++n)
            #pragma unroll
            for (int r = 0; r < 4; ++r)
                Ts[(m0 + quad*4 + r)*TPAD + n*16 + q16] = f2b(acc[n][r]);
        asm volatile("s_waitcnt lgkmcnt(0)\n\ts_barrier" ::: "memory");
        int j = t >> 2, kseg = t & 3;
        unsigned pk[8];
        #pragma unroll
        for (int i = 0; i < 8; ++i) {
            unsigned lo = Ts[(kseg*16 + 2*i    )*TPAD + j];
            unsigned hi = Ts[(kseg*16 + 2*i + 1)*TPAD + j];
            pk[i] = lo | (hi << 16);
        }
        int bb_ = r0 >> 11, k0g = r0 & (L_ - 1);
        unsigned short* dst = Vt + (size_t)(bb_*D_ + ct*64 + j)*L_ + k0g + kseg*16;
        *(uint4*)dst       = make_uint4(pk[0], pk[1], pk[2], pk[3]);
        *((uint4*)dst + 1) = make_uint4(pk[4], pk[5], pk[6], pk[7]);
    };

    if (!type) {
        // 8 phases: Wq halves H0..H7.  Epi (16 stores) after odd phases.
        #pragma unroll
        for (int h = 0; h < 8; ++h) {
            if (h == 7)      waitbar<0>();
            else if (h > 0) { if (h & 1) waitbar<4>(); else waitbar<20>(); }
            const int par = h & 1;
            acc[par*2] = z4; acc[par*2+1] = z4;
            compute_half(par);
            if (par) epi_qk(h >> 1);
            barOnly();
            if (h + 2 < 8) stage_W(W0, Wsb[par], (h+2)*32, w, lane);
        }
    } else {
        // 16 phases: Wk H0..H7 then Wv H0..H7.
        // K-epi (16 stores) after 1,3,5,7; V-epi (2 stores) after 9,11,13,15.
        #pragma unroll
        for (int h = 0; h < 16; ++h) {
            if (h == 15)     waitbar<0>();
            else if (h > 0) {
                if (h & 1)       waitbar<4>();
                else if (h <= 8) waitbar<20>();
                else             waitbar<6>();
            }
            const int par = h & 1;
            acc[par*2] = z4; acc[par*2+1] = z4;
            compute_half(par);
            if (par) { if (h < 8) epi_qk(h >> 1); else epi_v((h - 8) >> 1); }
            barOnly();
            if (h + 2 < 16) {
                const unsigned short* Ws_ = (h + 2 < 8) ? W0 : W1;
                stage_W(Ws_, Wsb[par], ((h + 2) & 7) * 32, w, lane);
            }
        }
    }

    {
        float* norm = type ? kn : qn;
        #pragma unroll
        for (int r = 0; r < 4; ++r) {
            float v = p4[r];
            v += __shfl_xor(v, 1, 16);
            v += __shfl_xor(v, 2, 16);
            v += __shfl_xor(v, 4, 16);
            v += __shfl_xor(v, 8, 16);
            if (q16 == 0) norm[r0 + m0 + quad*4 + r] = v;
        }
    }
}

// ---- staging helpers for 8-wave (512 thr) blocks ----
__device__ __forceinline__ void stage_K(const unsigned short* Kb, unsigned short* ks,
                                        int bk, int k0, int w, int lane) {
    #pragma unroll
    for (int p = 0; p < 2; ++p) {
        int slot = p*512 + w*64 + lane;
        int row  = slot >> 5;
        int blk  = slot & 31;
        gl16(Kb + (size_t)(bk + k0 + row)*D_ + ((blk ^ (row & 15))*8),
             ks + (size_t)(p*512 + w*64)*8);
    }
}
__device__ __forceinline__ void stage_V(const unsigned short* Vt, unsigned short* vs,
                                        int bD, int k0, int w, int lane) {
    #pragma unroll
    for (int p = 0; p < 2; ++p) {
        int slot = p*512 + w*64 + lane;
        int d    = slot >> 2;
        int blk  = slot & 3;
        gl16(Vt + (size_t)(bD + d)*L_ + k0 + ((blk ^ ((d >> 1) & 3))*8),
             vs + (size_t)(p*512 + w*64)*8);
    }
}

// -------- K2: attention core, counted-vmcnt 2-deep pipeline (two-barrier) ---
// 256 blocks x 8 waves; block owns 128 q rows, streams its batch's K/V once.
// Per tile: {vmcnt(N); s_barrier; QK->softmax->E-export->PV; s_barrier;
//            stage(t+2)}.  The second barrier gives the recycled buffer a full
// extra barrier of separation from its last readers (replay-race hardening;
// single-barrier variant tripped the post-timing determinism check in R10).
__global__ __launch_bounds__(512) void attnpv_kernel(
    const unsigned short* __restrict__ Qb, const unsigned short* __restrict__ Kb,
    const unsigned short* __restrict__ Vt,
    const float* __restrict__ qn, const float* __restrict__ kn,
    const unsigned char* __restrict__ mask,
    unsigned short* __restrict__ Eb,
    float* __restrict__ rowsum, float* __restrict__ att_out)
{
    __shared__ unsigned short Ks[3][32*256];    // 3 x 16 KB
    __shared__ unsigned short Vs[3][256*32];    // 3 x 16 KB
    __shared__ unsigned short Es[8][16*EPAD];   // per-wave E tile (10 KB)
    __shared__ float         knS[L_];           // 8 KB
    __shared__ unsigned char mkS[L_];           // 2 KB

    const int t  = threadIdx.x;
    const int s  = blockIdx.y * 16 + blockIdx.x;
    const int b  = ((s & 7) << 1) | (s >> 7);
    const int q0 = ((s >> 3) & 15) * 128;
    const int bk = b * L_;
    const int bD = b * D_;
    const int w = t >> 6, lane = t & 63, q16 = lane & 15, quad = lane >> 4;
    const int qrow = bk + q0 + w*16;

    *(float4*)&knS[t*4] = *(const float4*)&kn[bk + t*4];
    ((unsigned*)mkS)[t] = ((const unsigned*)(mask + bk))[t];

    s8v qa[8];
    float qnr[4];
    #pragma unroll
    for (int c = 0; c < 8; ++c)
        qa[c] = *(const s8v*)(Qb + (size_t)(qrow + q16)*D_ + c*32 + quad*8);
    #pragma unroll
    for (int r = 0; r < 4; ++r)
        qnr[r] = qn[qrow + quad*4 + r];

    unsigned short* ebase = Eb + (size_t)(qrow + (lane >> 2))*L_ + (lane & 3)*8;
    const unsigned short* esrc = &Es[w][(lane >> 2)*EPAD + (lane & 3)*8];

    float rs[4] = {0.f, 0.f, 0.f, 0.f};
    const f4v z4 = {0.f, 0.f, 0.f, 0.f};
    f4v O[16];
    #pragma unroll
    for (int n = 0; n < 16; ++n) O[n] = z4;

    auto do_tile = [&](int kt, int cur) {
        const int k0 = kt * 32;
        float kcv[2]; int mkv[2];
        #pragma unroll
        for (int n = 0; n < 2; ++n) {
            kcv[n] = knS[k0 + n*16 + q16];
            mkv[n] = mkS[k0 + n*16 + q16];
        }
        #pragma unroll
        for (int n = 0; n < 2; ++n) {
            f4v s4 = z4;
            __builtin_amdgcn_s_setprio(1);
            #pragma unroll
            for (int c = 0; c < 8; ++c) {
                s8v bb = *(const s8v*)(Ks[cur] + (n*16 + q16)*256 + (((c*4+quad) ^ q16)*8));
                s4 = __builtin_amdgcn_mfma_f32_16x16x32_bf16(qa[c], bb, s4, 0, 0, 0);
            }
            __builtin_amdgcn_s_setprio(0);
            #pragma unroll
            for (int r = 0; r < 4; ++r) {
                float d2 = fmaf(-2.0f, s4[r], qnr[r] + kcv[n]);
                float dist = sqrtf(fmaxf(d2, 0.f));
                float E = mkv[n] ? 0.f : __expf(__expf(-dist));
                rs[r] += E;
                Es[w][(quad*4 + r)*EPAD + n*16 + q16] = f2b(E);
            }
        }
        // E export issued BEFORE PV: store overlaps the 16 PV MFMAs
        *(s8v*)(ebase + k0) = *(const s8v*)esrc;
        s8v af = *(const s8v*)(&Es[w][q16*EPAD + quad*8]);
        __builtin_amdgcn_s_setprio(1);
        #pragma unroll
        for (int n = 0; n < 16; ++n) {
            s8v vb = *(const s8v*)(Vs[cur] + (n*16 + q16)*32 +
                                   ((quad ^ ((q16 >> 1) & 3))*8));
            O[n] = __builtin_amdgcn_mfma_f32_16x16x32_bf16(af, vb, O[n], 0, 0, 0);
        }
        __builtin_amdgcn_s_setprio(0);
    };

    stage_K(Kb, Ks[0], bk, 0,  w, lane);  stage_V(Vt, Vs[0], bD, 0,  w, lane);
    stage_K(Kb, Ks[1], bk, 32, w, lane);  stage_V(Vt, Vs[1], bD, 32, w, lane);

    asm volatile("s_waitcnt vmcnt(4) lgkmcnt(0)\n\ts_barrier" ::: "memory");
    do_tile(0, 0);
    asm volatile("s_barrier" ::: "memory");
    stage_K(Kb, Ks[2], bk, 64, w, lane);  stage_V(Vt, Vs[2], bD, 64, w, lane);

    int cur = 1;
    for (int kt = 1; kt <= 62; ++kt) {
        asm volatile("s_waitcnt vmcnt(5)\n\ts_barrier" ::: "memory");
        do_tile(kt, cur);
        asm volatile("s_barrier" ::: "memory");
        if (kt <= 61) {
            int nb = cur - 1; if (nb < 0) nb = 2;   // (kt+2) % 3
            stage_K(Kb, Ks[nb], bk, (kt+2)*32, w, lane);
            stage_V(Vt, Vs[nb], bD, (kt+2)*32, w, lane);
        }
        cur = (cur == 2) ? 0 : cur + 1;
    }
    asm volatile("s_waitcnt vmcnt(1)\n\ts_barrier" ::: "memory");
    do_tile(63, 0);

    float inv4[4];
    #pragma unroll
    for (int r = 0; r < 4; ++r) {
        float v = rs[r];
        v += __shfl_xor(v, 1, 16);
        v += __shfl_xor(v, 2, 16);
        v += __shfl_xor(v, 4, 16);
        v += __shfl_xor(v, 8, 16);
        inv4[r] = 1.0f / v;
        if (q16 == 0) rowsum[qrow + quad*4 + r] = v;
    }
    #pragma unroll
    for (int n = 0; n < 16; ++n)
        #pragma unroll
        for (int r = 0; r < 4; ++r)
            __builtin_nontemporal_store(O[n][r] * inv4[r],
                att_out + (size_t)(qrow + quad*4 + r)*D_ + n*16 + q16);
}

// -------- K3: attn = E * (1/rowsum), pure streaming, full occupancy --------
__global__ __launch_bounds__(256) void norm_kernel(
    const unsigned short* __restrict__ Eb,
    const float* __restrict__ rowsum,
    float* __restrict__ attn_out)
{
    const int row = blockIdx.x;
    const int t   = threadIdx.x;
    const float inv = 1.0f / rowsum[row];
    const size_t base = (size_t)row * L_ + t*8;

    s8v e = *(const s8v*)(Eb + base);
    f4n o0, o1;
    o0.x = __builtin_bit_cast(float, ((unsigned)(unsigned short)e[0]) << 16) * inv;
    o0.y = __builtin_bit_cast(float, ((unsigned)(unsigned short)e[1]) << 16) * inv;
    o0.z = __builtin_bit_cast(float, ((unsigned)(unsigned short)e[2]) << 16) * inv;
    o0.w = __builtin_bit_cast(float, ((unsigned)(unsigned short)e[3]) << 16) * inv;
    o1.x = __builtin_bit_cast(float, ((unsigned)(unsigned short)e[4]) << 16) * inv;
    o1.y = __builtin_bit_cast(float, ((unsigned)(unsigned short)e[5]) << 16) * inv;
    o1.z = __builtin_bit_cast(float, ((unsigned)(unsigned short)e[6]) << 16) * inv;
    o1.w = __builtin_bit_cast(float, ((unsigned)(unsigned short)e[7]) << 16) * inv;
    __builtin_nontemporal_store(o0, (f4n*)(attn_out + base));
    __builtin_nontemporal_store(o1, (f4n*)(attn_out + base + 4));
}

extern "C" void kernel_launch(void* const* d_in, const int* in_sizes, int n_in,
                              void* d_out, int out_size, void* d_ws, size_t ws_size,
                              hipStream_t stream) {
    (void)in_sizes; (void)n_in; (void)out_size; (void)ws_size;
    const float* x  = (const float*)d_in[0];
    const float* y  = (const float*)d_in[1];
    const unsigned char* mask = (const unsigned char*)d_in[2];
    const float* Wq = (const float*)d_in[3];
    const float* Wk = (const float*)d_in[4];
    const float* Wv = (const float*)d_in[5];

    // ws: Qb | Kb | Vt (bf16) | qn | kn | rowsum (fp32) | Eb (bf16) | Wb (bf16)
    char* ws = (char*)d_ws;
    unsigned short* Qb = (unsigned short*)ws;
    unsigned short* Kb = Qb + (size_t)NROW * D_;
    unsigned short* Vt = Kb + (size_t)NROW * D_;
    float* qn     = (float*)(ws + 3 * (size_t)NROW * D_ * 2);
    float* kn     = qn + NROW;
    float* rowsum = kn + NROW;
    unsigned short* Eb = (unsigned short*)(rowsum + NROW);
    unsigned short* Wb = Eb + (size_t)NROW * L_;

    float* att_out = (float*)d_out;                       // [B, LQ, D]
    float* attn    = att_out + (size_t)NROW * D_;         // [B, LQ, LK]

    wconv_kernel<<<dim3(4, 3), 256, 0, stream>>>(Wq, Wk, Wv, Wb);
    qkv_kernel<<<dim3(512, 2), 256, 0, stream>>>(x, y, Wb, Qb, Kb, Vt, qn, kn);
    attnpv_kernel<<<dim3(16, 16), 512, 0, stream>>>(Qb, Kb, Vt, qn, kn, mask,
                                                    Eb, rowsum, att_out);
    norm_kernel<<<dim3(NROW), 256, 0, stream>>>(Eb, rowsum, attn);
}